// Round 1
// baseline (674.274 us; speedup 1.0000x reference)
//
#include <hip/hip_runtime.h>

// Problem dims (fixed by setup_inputs)
#define B_   64
#define C_   256
#define T_   1024
#define H_   512
#define G_   192   // 64 tx groups + 128 rx groups (b*2+i)
#define BETA_   0.9f
#define THRESH_ 0.75f

// d_out layout (reference return order, flattened)
#define OUT_DIST 0
#define OUT_AZI  (64*512)
#define OUT_ELE  (2*64*512)
#define OUT_RX   (3*64*512)
#define OUT_SP   (3*64*512 + 64*2*256*1024)

// Fused kernel: per block = one group g, one 64-wide o-tile.
// Loops t-tiles of 128: fp32 GEMM (K=256) -> LDS tile -> LIF scan (wave0,
// carry in registers) -> coalesced spike tile write (rx) / count only (tx).
__global__ __launch_bounds__(128) void lif_gemm_scan(
    const float* __restrict__ transmit, const float* __restrict__ receive,
    const float* __restrict__ Wtx, const float* __restrict__ btx,
    const float* __restrict__ Wrx, const float* __restrict__ brx,
    float* __restrict__ out, float* __restrict__ wsF)
{
    // LDS: K-loop phase uses Slds[32][128] (4096 f) + Wlds[32][64] (2048 f);
    // epilogue phase reuses the same storage as Mlds[128][68] (8704 f).
    __shared__ float lds[128 * 68];
    float* Slds = lds;
    float* Wlds = lds + 4096;
    float* Mlds = lds;

    const int tid = threadIdx.x;
    const int bx  = blockIdx.x;
    const int ot  = bx / G_;       // 0..3  (same-g blocks are 192 apart -> same XCD)
    const int g   = bx % G_;       // 0..191
    const int o0  = ot * 64;
    const bool isRx = (g >= 64);

    const float* Sg = isRx ? (receive + (size_t)(g - 64) * C_ * T_)
                           : (transmit + (size_t)g * C_ * T_);
    const float* Wp = isRx ? Wrx : Wtx;
    const float* bp = isRx ? brx : btx;

    const int ti = tid & 15;       // t-group 0..15
    const int oi = tid >> 4;       // o-group 0..7
    const int tb = ti * 4;         // thread t rows: {tb..tb+3, 64+tb..64+tb+3}
    const int ob = oi * 4;         // thread o cols: {ob..ob+3, 32+ob..32+ob+3}

    float bias[2][4];
#pragma unroll
    for (int os = 0; os < 2; ++os)
#pragma unroll
        for (int j = 0; j < 4; ++j)
            bias[os][j] = bp[o0 + os * 32 + ob + j];

    // LIF carry for scan lane (wave0: lane = o within tile)
    float mem = 0.f, spk = 0.f, cnt = 0.f;

    for (int tt = 0; tt < 8; ++tt) {
        const int t0 = tt * 128;

        float acc[8][8];
#pragma unroll
        for (int ii = 0; ii < 8; ++ii)
#pragma unroll
            for (int jj = 0; jj < 8; ++jj)
                acc[ii][jj] = bias[jj >> 2][jj & 3];

        for (int kk = 0; kk < 8; ++kk) {
            const int c0 = kk * 32;
            // Stage S chunk [32 c][128 t], coalesced float4 rows
#pragma unroll
            for (int p = 0; p < 8; ++p) {
                int idx = tid + p * 128;          // 0..1023 float4s
                int c = idx >> 5, t4 = idx & 31;
                float4 v = *(const float4*)(Sg + (size_t)(c0 + c) * T_ + t0 + t4 * 4);
                *(float4*)(Slds + c * 128 + t4 * 4) = v;
            }
            // Stage W chunk transposed: Wlds[c][o] (stride 64)
#pragma unroll
            for (int p = 0; p < 4; ++p) {
                int idx = tid + p * 128;          // 0..511 float4s
                int o = idx >> 3, c4 = idx & 7;
                float4 w = *(const float4*)(Wp + (size_t)(o0 + o) * C_ + c0 + c4 * 4);
                Wlds[(c4 * 4 + 0) * 64 + o] = w.x;
                Wlds[(c4 * 4 + 1) * 64 + o] = w.y;
                Wlds[(c4 * 4 + 2) * 64 + o] = w.z;
                Wlds[(c4 * 4 + 3) * 64 + o] = w.w;
            }
            __syncthreads();
#pragma unroll 8
            for (int k = 0; k < 32; ++k) {
                float4 a0 = *(const float4*)(Slds + k * 128 + tb);
                float4 a1 = *(const float4*)(Slds + k * 128 + 64 + tb);
                float4 b0 = *(const float4*)(Wlds + k * 64 + ob);
                float4 b1 = *(const float4*)(Wlds + k * 64 + 32 + ob);
                float a[8]  = {a0.x, a0.y, a0.z, a0.w, a1.x, a1.y, a1.z, a1.w};
                float bv[8] = {b0.x, b0.y, b0.z, b0.w, b1.x, b1.y, b1.z, b1.w};
#pragma unroll
                for (int ii = 0; ii < 8; ++ii)
#pragma unroll
                    for (int jj = 0; jj < 8; ++jj)
                        acc[ii][jj] += a[ii] * bv[jj];
            }
            __syncthreads();
        }

        // acc -> Mlds[t][o] (stride 68, 16B-aligned columns)
#pragma unroll
        for (int ii = 0; ii < 8; ++ii) {
            int t = (ii >> 2) * 64 + tb + (ii & 3);
#pragma unroll
            for (int os = 0; os < 2; ++os) {
                float4 v = make_float4(acc[ii][os * 4 + 0], acc[ii][os * 4 + 1],
                                       acc[ii][os * 4 + 2], acc[ii][os * 4 + 3]);
                *(float4*)(Mlds + t * 68 + os * 32 + ob) = v;
            }
        }
        __syncthreads();

        // LIF scan: wave0, lane = o column; sequential over 128 steps
        if (tid < 64) {
#pragma unroll 4
            for (int t = 0; t < 128; ++t) {
                float x = Mlds[t * 68 + tid];
                mem = BETA_ * mem + x - spk * THRESH_;
                spk = (mem > THRESH_) ? 1.0f : 0.0f;
                cnt += spk;
                Mlds[t * 68 + tid] = spk;
            }
        }
        __syncthreads();

        // rx: write spike tile [64 o][128 t] to global, t-major coalesced
        if (isRx) {
            float* dst = out + (size_t)OUT_RX + (size_t)(g - 64) * C_ * T_
                         + (size_t)o0 * T_ + t0;
            int m = tid & 7;
            int orow0 = tid >> 3;  // 0..15
#pragma unroll
            for (int p = 0; p < 4; ++p) {
                int orow = orow0 + p * 16;
#pragma unroll
                for (int q = 0; q < 4; ++q) {
                    int tq = m * 4 + q * 32;
                    float4 v = make_float4(Mlds[(tq + 0) * 68 + orow],
                                           Mlds[(tq + 1) * 68 + orow],
                                           Mlds[(tq + 2) * 68 + orow],
                                           Mlds[(tq + 3) * 68 + orow]);
                    *(float4*)(dst + (size_t)orow * T_ + tq) = v;
                }
            }
        }
        __syncthreads();
    }

    // spike sums
    if (tid < 64) {
        if (isRx) out[(size_t)OUT_SP + (size_t)(g - 64) * C_ + o0 + tid] = cnt;
        else      wsF[(size_t)g * C_ + o0 + tid] = cnt;
    }
}

// Heads: layernorm over C=256 + GEMV to H=512, 3 heads x 64 batches
__global__ __launch_bounds__(256) void heads_kernel(
    const float* __restrict__ wsF, const float* __restrict__ sp,
    const float* __restrict__ Wd, const float* __restrict__ bd,
    const float* __restrict__ Wa, const float* __restrict__ ba,
    const float* __restrict__ We, const float* __restrict__ be,
    const float* __restrict__ gd, const float* __restrict__ ga, const float* __restrict__ ge,
    const float* __restrict__ based, const float* __restrict__ basea, const float* __restrict__ basee,
    float* __restrict__ out)
{
    __shared__ float fv[256];
    __shared__ float red[8];
    const int tid = threadIdx.x;
    const int hd  = blockIdx.x >> 6;   // 0:dist 1:azi 2:ele
    const int b   = blockIdx.x & 63;

    float f;
    if (hd == 0) {
        f = wsF[b * 256 + tid] * (1.f / 1024.f);
    } else {
        float l = sp[(2 * b) * 256 + tid];
        float r = sp[(2 * b + 1) * 256 + tid];
        f = ((hd == 1) ? (l - r) : (l + r)) * (1.f / 1024.f);
    }

    float v = f;
#pragma unroll
    for (int off = 32; off > 0; off >>= 1) v += __shfl_down(v, off, 64);
    if ((tid & 63) == 0) red[tid >> 6] = v;
    __syncthreads();
    float mu = (red[0] + red[1] + red[2] + red[3]) * (1.f / 256.f);

    float d = f - mu;
    v = d * d;
#pragma unroll
    for (int off = 32; off > 0; off >>= 1) v += __shfl_down(v, off, 64);
    if ((tid & 63) == 0) red[4 + (tid >> 6)] = v;
    __syncthreads();
    float var  = (red[4] + red[5] + red[6] + red[7]) * (1.f / 256.f);
    float rstd = rsqrtf(var + 1e-5f);
    fv[tid] = d * rstd;
    __syncthreads();

    const float* W    = (hd == 0) ? Wd : (hd == 1) ? Wa : We;
    const float* bb   = (hd == 0) ? bd : (hd == 1) ? ba : be;
    const float* base = (hd == 0) ? based : (hd == 1) ? basea : basee;
    float gain = (hd == 0) ? gd[0] : (hd == 1) ? ga[0] : ge[0];
    float s = 0.3f / (1.f + expf(-gain));

    const float4* fv4 = (const float4*)fv;
#pragma unroll
    for (int hh = 0; hh < 2; ++hh) {
        int h = tid + hh * 256;
        const float4* W4 = (const float4*)(W + (size_t)h * 256);
        float acc = 0.f;
#pragma unroll 8
        for (int c = 0; c < 64; ++c) {
            float4 w = W4[c];
            float4 x = fv4[c];
            acc += w.x * x.x + w.y * x.y + w.z * x.z + w.w * x.w;
        }
        float r = acc + bb[h];
        float o = base[b * 512 + h] + s * r;
        out[(size_t)hd * (64 * 512) + b * 512 + h] = fmaxf(o, 0.f);
    }
}

extern "C" void kernel_launch(void* const* d_in, const int* in_sizes, int n_in,
                              void* d_out, int out_size, void* d_ws, size_t ws_size,
                              hipStream_t stream)
{
    const float* transmit = (const float*)d_in[0];
    const float* receive  = (const float*)d_in[1];
    const float* based    = (const float*)d_in[2];
    const float* basea    = (const float*)d_in[3];
    const float* basee    = (const float*)d_in[4];
    const float* Wtx      = (const float*)d_in[5];
    const float* btx      = (const float*)d_in[6];
    const float* Wrx      = (const float*)d_in[7];
    const float* brx      = (const float*)d_in[8];
    const float* Wd       = (const float*)d_in[9];
    const float* bd       = (const float*)d_in[10];
    const float* Wa       = (const float*)d_in[11];
    const float* ba       = (const float*)d_in[12];
    const float* We       = (const float*)d_in[13];
    const float* be       = (const float*)d_in[14];
    const float* gd       = (const float*)d_in[15];
    const float* ga       = (const float*)d_in[16];
    const float* ge       = (const float*)d_in[17];
    float* out = (float*)d_out;
    float* wsF = (float*)d_ws;   // 64*256 floats: tx spike counts

    hipLaunchKernelGGL(lif_gemm_scan, dim3(768), dim3(128), 0, stream,
                       transmit, receive, Wtx, btx, Wrx, brx, out, wsF);
    hipLaunchKernelGGL(heads_kernel, dim3(192), dim3(256), 0, stream,
                       wsF, out + (size_t)OUT_SP, Wd, bd, Wa, ba, We, be,
                       gd, ga, ge, based, basea, basee, out);
}

// Round 2
// 590.920 us; speedup vs baseline: 1.1411x; 1.1411x over previous
//
#include <hip/hip_runtime.h>

// Problem dims (fixed by setup_inputs)
#define B_   64
#define C_   256
#define T_   1024
#define H_   512
#define G_   192   // 64 tx groups + 128 rx groups (b*2+i)
#define BETA_   0.9f
#define THRESH_ 0.75f

// d_out layout (reference return order, flattened)
#define OUT_DIST 0
#define OUT_AZI  (64*512)
#define OUT_ELE  (2*64*512)
#define OUT_RX   (3*64*512)
#define OUT_SP   (3*64*512 + 64*2*256*1024)

// ws layout (new path), in floats:
//   [0, 65536)        Wt_tx  (W_tx transposed, [c][o])
//   [65536, 131072)   Wt_rx
//   [131072, 147456)  tx spike counts (64 g x 256 o)
//   [147456, ...)     mixed_tx chunk area (Gc * 1024 * 256 floats)
#define WS_WT_TX   0
#define WS_WT_RX   65536
#define WS_CNT     131072
#define WS_MIXED   147456

// ---------------------------------------------------------------------------
// New path kernels
// ---------------------------------------------------------------------------

// Transpose both 256x256 weight matrices into ws: Wt[c][o] = W[o][c]
__global__ __launch_bounds__(256) void transpose_w(
    const float* __restrict__ Wtx, const float* __restrict__ Wrx,
    float* __restrict__ ws)
{
    __shared__ float tile[32][33];
    const int b = blockIdx.x;            // 0..127; b<64 -> tx
    const float* src = (b < 64) ? Wtx : Wrx;
    float* dst = ws + ((b < 64) ? WS_WT_TX : WS_WT_RX);
    const int tb = b & 63;
    const int r0 = (tb >> 3) * 32;       // o-tile
    const int c0 = (tb & 7) * 32;        // c-tile
    const int tx = threadIdx.x & 31, ty = threadIdx.x >> 5;  // 32x8
#pragma unroll
    for (int dy = 0; dy < 32; dy += 8)
        tile[ty + dy][tx] = src[(size_t)(r0 + ty + dy) * 256 + c0 + tx];
    __syncthreads();
#pragma unroll
    for (int dy = 0; dy < 32; dy += 8)
        dst[(size_t)(c0 + ty + dy) * 256 + r0 + tx] = tile[tx][ty + dy];
}

// fp32 GEMM: mixed[g][t][o] = sum_c S[g][c][t] * Wt[c][o] + bias[o]
// Tile 128(t) x 128(o) x 32(c); 256 threads, 8x8 micro-tile.
__global__ __launch_bounds__(256, 4) void gemm_mix(
    const float* __restrict__ S, const float* __restrict__ Wt,
    const float* __restrict__ bias, float* __restrict__ mixed)
{
    __shared__ float Slds[32 * 128];
    __shared__ float Wlds[32 * 128];

    const int tid = threadIdx.x;
    const int t0 = blockIdx.x * 128;
    const int o0 = blockIdx.y * 128;
    const size_t g = blockIdx.z;
    const float* Sg = S + g * (size_t)(C_ * T_);
    float* Mg = mixed + g * (size_t)(T_ * C_);

    const int ti = tid & 15;   // t-group
    const int oi = tid >> 4;   // o-group
    const int tb = ti * 4;
    const int ob = oi * 4;

    float acc[8][8];
#pragma unroll
    for (int jj = 0; jj < 8; ++jj) {
        float bj = bias[o0 + (jj >> 2) * 64 + ob + (jj & 3)];
#pragma unroll
        for (int ii = 0; ii < 8; ++ii) acc[ii][jj] = bj;
    }

    for (int kk = 0; kk < 8; ++kk) {
        const int c0 = kk * 32;
        // Stage S rows [32 c][128 t] and Wt rows [32 c][128 o]; both coalesced.
#pragma unroll
        for (int p = 0; p < 4; ++p) {
            int idx = tid + p * 256;          // 0..1023
            int c = idx >> 5, x4 = idx & 31;
            *(float4*)(Slds + c * 128 + x4 * 4) =
                *(const float4*)(Sg + (size_t)(c0 + c) * T_ + t0 + x4 * 4);
            *(float4*)(Wlds + c * 128 + x4 * 4) =
                *(const float4*)(Wt + (size_t)(c0 + c) * 256 + o0 + x4 * 4);
        }
        __syncthreads();
#pragma unroll 8
        for (int k = 0; k < 32; ++k) {
            float4 a0 = *(const float4*)(Slds + k * 128 + tb);
            float4 a1 = *(const float4*)(Slds + k * 128 + 64 + tb);
            float4 b0 = *(const float4*)(Wlds + k * 128 + ob);
            float4 b1 = *(const float4*)(Wlds + k * 128 + 64 + ob);
            float a[8]  = {a0.x, a0.y, a0.z, a0.w, a1.x, a1.y, a1.z, a1.w};
            float bv[8] = {b0.x, b0.y, b0.z, b0.w, b1.x, b1.y, b1.z, b1.w};
#pragma unroll
            for (int ii = 0; ii < 8; ++ii)
#pragma unroll
                for (int jj = 0; jj < 8; ++jj)
                    acc[ii][jj] += a[ii] * bv[jj];
        }
        __syncthreads();
    }

    // Write mixed[t][o], two float4 per acc row
#pragma unroll
    for (int ii = 0; ii < 8; ++ii) {
        int trow = (ii >> 2) * 64 + tb + (ii & 3);
        float* dst = Mg + (size_t)(t0 + trow) * 256 + o0;
        *(float4*)(dst + ob) =
            make_float4(acc[ii][0], acc[ii][1], acc[ii][2], acc[ii][3]);
        *(float4*)(dst + 64 + ob) =
            make_float4(acc[ii][4], acc[ii][5], acc[ii][6], acc[ii][7]);
    }
}

// Combined LIF scan.
// Blocks [0,128): rx group g = blk; reads mixed in-place from out rx region
//   ([t][o] layout), scans, then rewrites region as spikes in [o][t] layout.
//   In-place is legal: block-wide barrier between last read and first write.
// Blocks [128, 128+nTx): tx group; counts only.
__global__ __launch_bounds__(256) void scan_combined(
    float* __restrict__ outRx, float* __restrict__ spOut,
    const float* __restrict__ mixedTx, float* __restrict__ txCounts, int nTx)
{
    __shared__ float lds[64 * 257];
    const int blk = blockIdx.x;
    const int tid = threadIdx.x;

    if (blk < 128) {
        float* base = outRx + (size_t)blk * (T_ * 256);
        unsigned int bits[32];
        float mem = 0.f, spk = 0.f, cnt = 0.f;
        for (int w = 0; w < 32; ++w) {
            float x[32];
#pragma unroll
            for (int j = 0; j < 32; ++j)
                x[j] = base[(size_t)(w * 32 + j) * 256 + tid];
            unsigned int word = 0u;
#pragma unroll
            for (int j = 0; j < 32; ++j) {
                mem = BETA_ * mem + x[j] - spk * THRESH_;
                spk = (mem > THRESH_) ? 1.0f : 0.0f;
                cnt += spk;
                word |= (mem > THRESH_) ? (1u << j) : 0u;
            }
            bits[w] = word;
        }
        __syncthreads();   // all reads of this g complete before any write

        for (int c = 0; c < 16; ++c) {
            // unpack chunk of 64 t into LDS [t][o], stride 257 (conflict-free)
#pragma unroll
            for (int j = 0; j < 64; ++j) {
                int t = c * 64 + j;
                lds[j * 257 + tid] =
                    ((bits[t >> 5] >> (t & 31)) & 1u) ? 1.0f : 0.0f;
            }
            __syncthreads();
            const int m = tid & 15, r0 = tid >> 4;
#pragma unroll
            for (int p = 0; p < 16; ++p) {
                int o = p * 16 + r0;
                float4 v = make_float4(lds[(m * 4 + 0) * 257 + o],
                                       lds[(m * 4 + 1) * 257 + o],
                                       lds[(m * 4 + 2) * 257 + o],
                                       lds[(m * 4 + 3) * 257 + o]);
                *(float4*)(base + (size_t)o * T_ + c * 64 + m * 4) = v;
            }
            __syncthreads();
        }
        spOut[blk * 256 + tid] = cnt;
    } else {
        const int g = blk - 128;
        if (g >= nTx) return;
        const float* base = mixedTx + (size_t)g * (T_ * 256);
        float mem = 0.f, spk = 0.f, cnt = 0.f;
        for (int w = 0; w < 32; ++w) {
            float x[32];
#pragma unroll
            for (int j = 0; j < 32; ++j)
                x[j] = base[(size_t)(w * 32 + j) * 256 + tid];
#pragma unroll
            for (int j = 0; j < 32; ++j) {
                mem = BETA_ * mem + x[j] - spk * THRESH_;
                spk = (mem > THRESH_) ? 1.0f : 0.0f;
                cnt += spk;
            }
        }
        txCounts[g * 256 + tid] = cnt;
    }
}

// tx scan for the chunked-ws path: 64-thread blocks, counts only.
__global__ __launch_bounds__(64) void scan_tx_small(
    const float* __restrict__ mixedTx, float* __restrict__ txCounts, int g0)
{
    const int gl = blockIdx.x >> 2;
    const int o  = (blockIdx.x & 3) * 64 + threadIdx.x;
    const float* base = mixedTx + (size_t)gl * (T_ * 256);
    float mem = 0.f, spk = 0.f, cnt = 0.f;
    for (int w = 0; w < 32; ++w) {
        float x[32];
#pragma unroll
        for (int j = 0; j < 32; ++j)
            x[j] = base[(size_t)(w * 32 + j) * 256 + o];
#pragma unroll
        for (int j = 0; j < 32; ++j) {
            mem = BETA_ * mem + x[j] - spk * THRESH_;
            spk = (mem > THRESH_) ? 1.0f : 0.0f;
            cnt += spk;
        }
    }
    txCounts[(g0 + gl) * 256 + o] = cnt;
}

// ---------------------------------------------------------------------------
// Round-1 fused kernel, kept as fallback for tiny ws_size
// ---------------------------------------------------------------------------
__global__ __launch_bounds__(128) void lif_gemm_scan(
    const float* __restrict__ transmit, const float* __restrict__ receive,
    const float* __restrict__ Wtx, const float* __restrict__ btx,
    const float* __restrict__ Wrx, const float* __restrict__ brx,
    float* __restrict__ out, float* __restrict__ wsF)
{
    __shared__ float lds[128 * 68];
    float* Slds = lds;
    float* Wlds = lds + 4096;
    float* Mlds = lds;

    const int tid = threadIdx.x;
    const int bx  = blockIdx.x;
    const int ot  = bx / G_;
    const int g   = bx % G_;
    const int o0  = ot * 64;
    const bool isRx = (g >= 64);

    const float* Sg = isRx ? (receive + (size_t)(g - 64) * C_ * T_)
                           : (transmit + (size_t)g * C_ * T_);
    const float* Wp = isRx ? Wrx : Wtx;
    const float* bp = isRx ? brx : btx;

    const int ti = tid & 15;
    const int oi = tid >> 4;
    const int tb = ti * 4;
    const int ob = oi * 4;

    float bias[2][4];
#pragma unroll
    for (int os = 0; os < 2; ++os)
#pragma unroll
        for (int j = 0; j < 4; ++j)
            bias[os][j] = bp[o0 + os * 32 + ob + j];

    float mem = 0.f, spk = 0.f, cnt = 0.f;

    for (int tt = 0; tt < 8; ++tt) {
        const int t0 = tt * 128;
        float acc[8][8];
#pragma unroll
        for (int ii = 0; ii < 8; ++ii)
#pragma unroll
            for (int jj = 0; jj < 8; ++jj)
                acc[ii][jj] = bias[jj >> 2][jj & 3];

        for (int kk = 0; kk < 8; ++kk) {
            const int c0 = kk * 32;
#pragma unroll
            for (int p = 0; p < 8; ++p) {
                int idx = tid + p * 128;
                int c = idx >> 5, t4 = idx & 31;
                float4 v = *(const float4*)(Sg + (size_t)(c0 + c) * T_ + t0 + t4 * 4);
                *(float4*)(Slds + c * 128 + t4 * 4) = v;
            }
#pragma unroll
            for (int p = 0; p < 4; ++p) {
                int idx = tid + p * 128;
                int o = idx >> 3, c4 = idx & 7;
                float4 w = *(const float4*)(Wp + (size_t)(o0 + o) * C_ + c0 + c4 * 4);
                Wlds[(c4 * 4 + 0) * 64 + o] = w.x;
                Wlds[(c4 * 4 + 1) * 64 + o] = w.y;
                Wlds[(c4 * 4 + 2) * 64 + o] = w.z;
                Wlds[(c4 * 4 + 3) * 64 + o] = w.w;
            }
            __syncthreads();
#pragma unroll 8
            for (int k = 0; k < 32; ++k) {
                float4 a0 = *(const float4*)(Slds + k * 128 + tb);
                float4 a1 = *(const float4*)(Slds + k * 128 + 64 + tb);
                float4 b0 = *(const float4*)(Wlds + k * 64 + ob);
                float4 b1 = *(const float4*)(Wlds + k * 64 + 32 + ob);
                float a[8]  = {a0.x, a0.y, a0.z, a0.w, a1.x, a1.y, a1.z, a1.w};
                float bv[8] = {b0.x, b0.y, b0.z, b0.w, b1.x, b1.y, b1.z, b1.w};
#pragma unroll
                for (int ii = 0; ii < 8; ++ii)
#pragma unroll
                    for (int jj = 0; jj < 8; ++jj)
                        acc[ii][jj] += a[ii] * bv[jj];
            }
            __syncthreads();
        }

#pragma unroll
        for (int ii = 0; ii < 8; ++ii) {
            int t = (ii >> 2) * 64 + tb + (ii & 3);
#pragma unroll
            for (int os = 0; os < 2; ++os) {
                float4 v = make_float4(acc[ii][os * 4 + 0], acc[ii][os * 4 + 1],
                                       acc[ii][os * 4 + 2], acc[ii][os * 4 + 3]);
                *(float4*)(Mlds + t * 68 + os * 32 + ob) = v;
            }
        }
        __syncthreads();

        if (tid < 64) {
#pragma unroll 4
            for (int t = 0; t < 128; ++t) {
                float x = Mlds[t * 68 + tid];
                mem = BETA_ * mem + x - spk * THRESH_;
                spk = (mem > THRESH_) ? 1.0f : 0.0f;
                cnt += spk;
                Mlds[t * 68 + tid] = spk;
            }
        }
        __syncthreads();

        if (isRx) {
            float* dst = out + (size_t)OUT_RX + (size_t)(g - 64) * C_ * T_
                         + (size_t)o0 * T_ + t0;
            int m = tid & 7;
            int orow0 = tid >> 3;
#pragma unroll
            for (int p = 0; p < 4; ++p) {
                int orow = orow0 + p * 16;
#pragma unroll
                for (int q = 0; q < 4; ++q) {
                    int tq = m * 4 + q * 32;
                    float4 v = make_float4(Mlds[(tq + 0) * 68 + orow],
                                           Mlds[(tq + 1) * 68 + orow],
                                           Mlds[(tq + 2) * 68 + orow],
                                           Mlds[(tq + 3) * 68 + orow]);
                    *(float4*)(dst + (size_t)orow * T_ + tq) = v;
                }
            }
        }
        __syncthreads();
    }

    if (tid < 64) {
        if (isRx) out[(size_t)OUT_SP + (size_t)(g - 64) * C_ + o0 + tid] = cnt;
        else      wsF[(size_t)g * C_ + o0 + tid] = cnt;
    }
}

// Heads: layernorm over C=256 + GEMV to H=512, 3 heads x 64 batches
__global__ __launch_bounds__(256) void heads_kernel(
    const float* __restrict__ wsF, const float* __restrict__ sp,
    const float* __restrict__ Wd, const float* __restrict__ bd,
    const float* __restrict__ Wa, const float* __restrict__ ba,
    const float* __restrict__ We, const float* __restrict__ be,
    const float* __restrict__ gd, const float* __restrict__ ga, const float* __restrict__ ge,
    const float* __restrict__ based, const float* __restrict__ basea, const float* __restrict__ basee,
    float* __restrict__ out)
{
    __shared__ float fv[256];
    __shared__ float red[8];
    const int tid = threadIdx.x;
    const int hd  = blockIdx.x >> 6;
    const int b   = blockIdx.x & 63;

    float f;
    if (hd == 0) {
        f = wsF[b * 256 + tid] * (1.f / 1024.f);
    } else {
        float l = sp[(2 * b) * 256 + tid];
        float r = sp[(2 * b + 1) * 256 + tid];
        f = ((hd == 1) ? (l - r) : (l + r)) * (1.f / 1024.f);
    }

    float v = f;
#pragma unroll
    for (int off = 32; off > 0; off >>= 1) v += __shfl_down(v, off, 64);
    if ((tid & 63) == 0) red[tid >> 6] = v;
    __syncthreads();
    float mu = (red[0] + red[1] + red[2] + red[3]) * (1.f / 256.f);

    float d = f - mu;
    v = d * d;
#pragma unroll
    for (int off = 32; off > 0; off >>= 1) v += __shfl_down(v, off, 64);
    if ((tid & 63) == 0) red[4 + (tid >> 6)] = v;
    __syncthreads();
    float var  = (red[4] + red[5] + red[6] + red[7]) * (1.f / 256.f);
    float rstd = rsqrtf(var + 1e-5f);
    fv[tid] = d * rstd;
    __syncthreads();

    const float* W    = (hd == 0) ? Wd : (hd == 1) ? Wa : We;
    const float* bb   = (hd == 0) ? bd : (hd == 1) ? ba : be;
    const float* base = (hd == 0) ? based : (hd == 1) ? basea : basee;
    float gain = (hd == 0) ? gd[0] : (hd == 1) ? ga[0] : ge[0];
    float s = 0.3f / (1.f + expf(-gain));

    const float4* fv4 = (const float4*)fv;
#pragma unroll
    for (int hh = 0; hh < 2; ++hh) {
        int h = tid + hh * 256;
        const float4* W4 = (const float4*)(W + (size_t)h * 256);
        float acc = 0.f;
#pragma unroll 8
        for (int c = 0; c < 64; ++c) {
            float4 w = W4[c];
            float4 x = fv4[c];
            acc += w.x * x.x + w.y * x.y + w.z * x.z + w.w * x.w;
        }
        float r = acc + bb[h];
        float o = base[b * 512 + h] + s * r;
        out[(size_t)hd * (64 * 512) + b * 512 + h] = fmaxf(o, 0.f);
    }
}

extern "C" void kernel_launch(void* const* d_in, const int* in_sizes, int n_in,
                              void* d_out, int out_size, void* d_ws, size_t ws_size,
                              hipStream_t stream)
{
    const float* transmit = (const float*)d_in[0];
    const float* receive  = (const float*)d_in[1];
    const float* based    = (const float*)d_in[2];
    const float* basea    = (const float*)d_in[3];
    const float* basee    = (const float*)d_in[4];
    const float* Wtx      = (const float*)d_in[5];
    const float* btx      = (const float*)d_in[6];
    const float* Wrx      = (const float*)d_in[7];
    const float* brx      = (const float*)d_in[8];
    const float* Wd       = (const float*)d_in[9];
    const float* bd       = (const float*)d_in[10];
    const float* Wa       = (const float*)d_in[11];
    const float* ba       = (const float*)d_in[12];
    const float* We       = (const float*)d_in[13];
    const float* be       = (const float*)d_in[14];
    const float* gd       = (const float*)d_in[15];
    const float* ga       = (const float*)d_in[16];
    const float* ge       = (const float*)d_in[17];
    float* out = (float*)d_out;
    float* ws  = (float*)d_ws;

    const size_t needBase = (size_t)WS_MIXED * 4;           // 576 KB
    const size_t perG     = (size_t)T_ * C_ * 4;            // 1 MB per g

    if (ws_size >= needBase + perG) {
        // ---- new split path ----
        size_t availG = (ws_size - needBase) / perG;
        int gc = 1;
        while (gc * 2 <= 64 && (size_t)(gc * 2) <= availG) gc *= 2;

        float* wtTx   = ws + WS_WT_TX;
        float* wtRx   = ws + WS_WT_RX;
        float* txCnt  = ws + WS_CNT;
        float* mixedT = ws + WS_MIXED;
        float* outRx  = out + OUT_RX;
        float* spOut  = out + OUT_SP;

        hipLaunchKernelGGL(transpose_w, dim3(128), dim3(256), 0, stream,
                           Wtx, Wrx, ws);
        hipLaunchKernelGGL(gemm_mix, dim3(8, 2, 128), dim3(256), 0, stream,
                           receive, wtRx, brx, outRx);

        if (gc == 64) {
            hipLaunchKernelGGL(gemm_mix, dim3(8, 2, 64), dim3(256), 0, stream,
                               transmit, wtTx, btx, mixedT);
            hipLaunchKernelGGL(scan_combined, dim3(192), dim3(256), 0, stream,
                               outRx, spOut, mixedT, txCnt, 64);
        } else {
            hipLaunchKernelGGL(scan_combined, dim3(128), dim3(256), 0, stream,
                               outRx, spOut, mixedT, txCnt, 0);
            for (int g0 = 0; g0 < 64; g0 += gc) {
                hipLaunchKernelGGL(gemm_mix, dim3(8, 2, gc), dim3(256), 0, stream,
                                   transmit + (size_t)g0 * C_ * T_, wtTx, btx, mixedT);
                hipLaunchKernelGGL(scan_tx_small, dim3(gc * 4), dim3(64), 0, stream,
                                   mixedT, txCnt, g0);
            }
        }
        hipLaunchKernelGGL(heads_kernel, dim3(192), dim3(256), 0, stream,
                           txCnt, spOut, Wd, bd, Wa, ba, We, be,
                           gd, ga, ge, based, basea, basee, out);
    } else {
        // ---- fallback: round-1 fused path (needs only 64 KB ws) ----
        hipLaunchKernelGGL(lif_gemm_scan, dim3(768), dim3(128), 0, stream,
                           transmit, receive, Wtx, btx, Wrx, brx, out, ws);
        hipLaunchKernelGGL(heads_kernel, dim3(192), dim3(256), 0, stream,
                           ws, out + (size_t)OUT_SP, Wd, bd, Wa, ba, We, be,
                           gd, ga, ge, based, basea, basee, out);
    }
}

// Round 3
// 571.552 us; speedup vs baseline: 1.1797x; 1.0339x over previous
//
#include <hip/hip_runtime.h>

// Problem dims (fixed by setup_inputs)
#define B_   64
#define C_   256
#define T_   1024
#define H_   512
#define G_   192   // 64 tx groups + 128 rx groups (b*2+i)
#define BETA_   0.9f
#define THRESH_ 0.75f

// d_out layout (reference return order, flattened)
#define OUT_DIST 0
#define OUT_AZI  (64*512)
#define OUT_ELE  (2*64*512)
#define OUT_RX   (3*64*512)
#define OUT_SP   (3*64*512 + 64*2*256*1024)

// ws layout, in floats:
//   [0, 65536)        Wt_tx  (W_tx transposed, [c][o])
//   [65536, 131072)   Wt_rx
//   [131072, 147456)  tx spike counts (64 g x 256 o)
//   [147456, ...)     mixed_tx area (64 * 1024 * 256 floats) [tier 1 only]
#define WS_WT_TX   0
#define WS_WT_RX   65536
#define WS_CNT     131072
#define WS_MIXED   147456

// ---------------------------------------------------------------------------
// Transpose both 256x256 weight matrices into ws: Wt[c][o] = W[o][c]
__global__ __launch_bounds__(256) void transpose_w(
    const float* __restrict__ Wtx, const float* __restrict__ Wrx,
    float* __restrict__ ws)
{
    __shared__ float tile[32][33];
    const int b = blockIdx.x;            // 0..127; b<64 -> tx
    const float* src = (b < 64) ? Wtx : Wrx;
    float* dst = ws + ((b < 64) ? WS_WT_TX : WS_WT_RX);
    const int tb = b & 63;
    const int r0 = (tb >> 3) * 32;       // o-tile
    const int c0 = (tb & 7) * 32;        // c-tile
    const int tx = threadIdx.x & 31, ty = threadIdx.x >> 5;  // 32x8
#pragma unroll
    for (int dy = 0; dy < 32; dy += 8)
        tile[ty + dy][tx] = src[(size_t)(r0 + ty + dy) * 256 + c0 + tx];
    __syncthreads();
#pragma unroll
    for (int dy = 0; dy < 32; dy += 8)
        dst[(size_t)(c0 + ty + dy) * 256 + r0 + tx] = tile[tx][ty + dy];
}

// fp32 GEMM: mixed[g][o][t] = sum_c S[g][c][t] * Wt[c][o] + bias[o]
// Tile 128(t) x 128(o) x 32(c); 256 threads, 8x8 micro-tile.
// NOTE: output is [o][t] (transposed vs round 2) so the scan can run
// in-place per o-quarter block.
__global__ __launch_bounds__(256, 4) void gemm_mix(
    const float* __restrict__ S, const float* __restrict__ Wt,
    const float* __restrict__ bias, float* __restrict__ mixed)
{
    __shared__ float Slds[32 * 128];
    __shared__ float Wlds[32 * 128];

    const int tid = threadIdx.x;
    const int t0 = blockIdx.x * 128;
    const int o0 = blockIdx.y * 128;
    const size_t g = blockIdx.z;
    const float* Sg = S + g * (size_t)(C_ * T_);
    float* Mg = mixed + g * (size_t)(T_ * C_);

    const int ti = tid & 15;   // t-group
    const int oi = tid >> 4;   // o-group
    const int tb = ti * 4;
    const int ob = oi * 4;

    float acc[8][8];
#pragma unroll
    for (int jj = 0; jj < 8; ++jj) {
        float bj = bias[o0 + (jj >> 2) * 64 + ob + (jj & 3)];
#pragma unroll
        for (int ii = 0; ii < 8; ++ii) acc[ii][jj] = bj;
    }

    for (int kk = 0; kk < 8; ++kk) {
        const int c0 = kk * 32;
        // Stage S rows [32 c][128 t] and Wt rows [32 c][128 o]; both coalesced.
#pragma unroll
        for (int p = 0; p < 4; ++p) {
            int idx = tid + p * 256;          // 0..1023
            int c = idx >> 5, x4 = idx & 31;
            *(float4*)(Slds + c * 128 + x4 * 4) =
                *(const float4*)(Sg + (size_t)(c0 + c) * T_ + t0 + x4 * 4);
            *(float4*)(Wlds + c * 128 + x4 * 4) =
                *(const float4*)(Wt + (size_t)(c0 + c) * 256 + o0 + x4 * 4);
        }
        __syncthreads();
#pragma unroll 8
        for (int k = 0; k < 32; ++k) {
            float4 a0 = *(const float4*)(Slds + k * 128 + tb);
            float4 a1 = *(const float4*)(Slds + k * 128 + 64 + tb);
            float4 b0 = *(const float4*)(Wlds + k * 128 + ob);
            float4 b1 = *(const float4*)(Wlds + k * 128 + 64 + ob);
            float a[8]  = {a0.x, a0.y, a0.z, a0.w, a1.x, a1.y, a1.z, a1.w};
            float bv[8] = {b0.x, b0.y, b0.z, b0.w, b1.x, b1.y, b1.z, b1.w};
#pragma unroll
            for (int ii = 0; ii < 8; ++ii)
#pragma unroll
                for (int jj = 0; jj < 8; ++jj)
                    acc[ii][jj] += a[ii] * bv[jj];
        }
        __syncthreads();
    }

    // Transposed write: mixed[o][t]. Per jj: o fixed, two float4 runs of t.
    // Lanes: 16 ti give 64 contiguous t floats (256 B runs) -> coalesced.
#pragma unroll
    for (int jj = 0; jj < 8; ++jj) {
        int o = o0 + (jj >> 2) * 64 + ob + (jj & 3);
        float* dst = Mg + (size_t)o * T_ + t0;
        *(float4*)(dst + tb) =
            make_float4(acc[0][jj], acc[1][jj], acc[2][jj], acc[3][jj]);
        *(float4*)(dst + 64 + tb) =
            make_float4(acc[4][jj], acc[5][jj], acc[6][jj], acc[7][jj]);
    }
}

// LIF scan, one wave per (group, o-quarter). 768 blocks tier-1.
// rx blocks [0,512): g = blk>>2, quarter = blk&3; in-place over out rx region
//   (mixed [o][t] -> spikes [o][t], per-chunk read->scan->writeback; each
//   block touches only its own 64 rows).
// tx blocks [512,768): counts only, from ws mixed area.
__global__ __launch_bounds__(64) void scan_quarter(
    float* __restrict__ outRx, float* __restrict__ spOut,
    const float* __restrict__ mixedTx, float* __restrict__ txCnt)
{
    __shared__ float lds[32 * 65];
    const int blk = blockIdx.x;
    const int tid = threadIdx.x;
    const bool isRx = (blk < 512);
    const int li = isRx ? blk : (blk - 512);
    const int g = li >> 2, q = li & 3;

    float* base = isRx
        ? (outRx + (size_t)g * (C_ * T_) + (size_t)q * 64 * T_)
        : ((float*)mixedTx + (size_t)g * (C_ * T_) + (size_t)q * 64 * T_);

    float mem = 0.f, spk = 0.f, cnt = 0.f;

    float4 pre[8];
#pragma unroll
    for (int p = 0; p < 8; ++p) {
        int idx = tid + p * 64;
        pre[p] = *(const float4*)(base + (size_t)(idx >> 3) * T_ + (idx & 7) * 4);
    }

    for (int c = 0; c < 32; ++c) {
        // stage prefetched chunk into LDS [t][o], stride 65 (<=2-way banks)
#pragma unroll
        for (int p = 0; p < 8; ++p) {
            int idx = tid + p * 64;
            int o = idx >> 3, s4 = idx & 7;
            lds[(s4 * 4 + 0) * 65 + o] = pre[p].x;
            lds[(s4 * 4 + 1) * 65 + o] = pre[p].y;
            lds[(s4 * 4 + 2) * 65 + o] = pre[p].z;
            lds[(s4 * 4 + 3) * 65 + o] = pre[p].w;
        }
        __syncthreads();

        // prefetch next chunk (stays in flight during scan)
        if (c < 31) {
            const float* nb = base + (c + 1) * 32;
#pragma unroll
            for (int p = 0; p < 8; ++p) {
                int idx = tid + p * 64;
                pre[p] = *(const float4*)(nb + (size_t)(idx >> 3) * T_ + (idx & 7) * 4);
            }
        }

        if (isRx) {
#pragma unroll
            for (int j = 0; j < 32; ++j) {
                float x = lds[j * 65 + tid];
                mem = BETA_ * mem + x - spk * THRESH_;
                spk = (mem > THRESH_) ? 1.0f : 0.0f;
                cnt += spk;
                lds[j * 65 + tid] = spk;
            }
            __syncthreads();
            // coalesced writeback of spike chunk (in-place, region already read)
            float* dst = base + c * 32;
#pragma unroll
            for (int p = 0; p < 8; ++p) {
                int idx = tid + p * 64;
                int o = idx >> 3, s4 = idx & 7;
                float4 v = make_float4(lds[(s4 * 4 + 0) * 65 + o],
                                       lds[(s4 * 4 + 1) * 65 + o],
                                       lds[(s4 * 4 + 2) * 65 + o],
                                       lds[(s4 * 4 + 3) * 65 + o]);
                *(float4*)(dst + (size_t)o * T_ + s4 * 4) = v;
            }
            __syncthreads();
        } else {
#pragma unroll
            for (int j = 0; j < 32; ++j) {
                float x = lds[j * 65 + tid];
                mem = BETA_ * mem + x - spk * THRESH_;
                spk = (mem > THRESH_) ? 1.0f : 0.0f;
                cnt += spk;
            }
            __syncthreads();
        }
    }

    if (isRx) spOut[g * 256 + q * 64 + tid] = cnt;
    else      txCnt[g * 256 + q * 64 + tid] = cnt;
}

// rx-only variant for tier 2 (512 blocks)
__global__ __launch_bounds__(64) void scan_rx_only(
    float* __restrict__ outRx, float* __restrict__ spOut)
{
    __shared__ float lds[32 * 65];
    const int blk = blockIdx.x;
    const int tid = threadIdx.x;
    const int g = blk >> 2, q = blk & 3;
    float* base = outRx + (size_t)g * (C_ * T_) + (size_t)q * 64 * T_;

    float mem = 0.f, spk = 0.f, cnt = 0.f;
    float4 pre[8];
#pragma unroll
    for (int p = 0; p < 8; ++p) {
        int idx = tid + p * 64;
        pre[p] = *(const float4*)(base + (size_t)(idx >> 3) * T_ + (idx & 7) * 4);
    }
    for (int c = 0; c < 32; ++c) {
#pragma unroll
        for (int p = 0; p < 8; ++p) {
            int idx = tid + p * 64;
            int o = idx >> 3, s4 = idx & 7;
            lds[(s4 * 4 + 0) * 65 + o] = pre[p].x;
            lds[(s4 * 4 + 1) * 65 + o] = pre[p].y;
            lds[(s4 * 4 + 2) * 65 + o] = pre[p].z;
            lds[(s4 * 4 + 3) * 65 + o] = pre[p].w;
        }
        __syncthreads();
        if (c < 31) {
            const float* nb = base + (c + 1) * 32;
#pragma unroll
            for (int p = 0; p < 8; ++p) {
                int idx = tid + p * 64;
                pre[p] = *(const float4*)(nb + (size_t)(idx >> 3) * T_ + (idx & 7) * 4);
            }
        }
#pragma unroll
        for (int j = 0; j < 32; ++j) {
            float x = lds[j * 65 + tid];
            mem = BETA_ * mem + x - spk * THRESH_;
            spk = (mem > THRESH_) ? 1.0f : 0.0f;
            cnt += spk;
            lds[j * 65 + tid] = spk;
        }
        __syncthreads();
        float* dst = base + c * 32;
#pragma unroll
        for (int p = 0; p < 8; ++p) {
            int idx = tid + p * 64;
            int o = idx >> 3, s4 = idx & 7;
            float4 v = make_float4(lds[(s4 * 4 + 0) * 65 + o],
                                   lds[(s4 * 4 + 1) * 65 + o],
                                   lds[(s4 * 4 + 2) * 65 + o],
                                   lds[(s4 * 4 + 3) * 65 + o]);
            *(float4*)(dst + (size_t)o * T_ + s4 * 4) = v;
        }
        __syncthreads();
    }
    spOut[g * 256 + q * 64 + tid] = cnt;
}

// ---------------------------------------------------------------------------
// Tier-2/3 fallback: round-1 fused gemm+scan. txOnly variant counts tx only.
__global__ __launch_bounds__(128) void lif_gemm_scan_tx(
    const float* __restrict__ transmit,
    const float* __restrict__ Wtx, const float* __restrict__ btx,
    float* __restrict__ txCnt)
{
    __shared__ float lds[128 * 68];
    float* Slds = lds;
    float* Wlds = lds + 4096;
    float* Mlds = lds;

    const int tid = threadIdx.x;
    const int g  = blockIdx.x & 63;
    const int o0 = (blockIdx.x >> 6) * 64;

    const float* Sg = transmit + (size_t)g * C_ * T_;

    const int ti = tid & 15;
    const int oi = tid >> 4;
    const int tb = ti * 4;
    const int ob = oi * 4;

    float bias[2][4];
#pragma unroll
    for (int os = 0; os < 2; ++os)
#pragma unroll
        for (int j = 0; j < 4; ++j)
            bias[os][j] = btx[o0 + os * 32 + ob + j];

    float mem = 0.f, spk = 0.f, cnt = 0.f;

    for (int tt = 0; tt < 8; ++tt) {
        const int t0 = tt * 128;
        float acc[8][8];
#pragma unroll
        for (int ii = 0; ii < 8; ++ii)
#pragma unroll
            for (int jj = 0; jj < 8; ++jj)
                acc[ii][jj] = bias[jj >> 2][jj & 3];

        for (int kk = 0; kk < 8; ++kk) {
            const int c0 = kk * 32;
#pragma unroll
            for (int p = 0; p < 8; ++p) {
                int idx = tid + p * 128;
                int c = idx >> 5, t4 = idx & 31;
                *(float4*)(Slds + c * 128 + t4 * 4) =
                    *(const float4*)(Sg + (size_t)(c0 + c) * T_ + t0 + t4 * 4);
            }
#pragma unroll
            for (int p = 0; p < 4; ++p) {
                int idx = tid + p * 128;
                int o = idx >> 3, c4 = idx & 7;
                float4 w = *(const float4*)(Wtx + (size_t)(o0 + o) * C_ + c0 + c4 * 4);
                Wlds[(c4 * 4 + 0) * 64 + o] = w.x;
                Wlds[(c4 * 4 + 1) * 64 + o] = w.y;
                Wlds[(c4 * 4 + 2) * 64 + o] = w.z;
                Wlds[(c4 * 4 + 3) * 64 + o] = w.w;
            }
            __syncthreads();
#pragma unroll 8
            for (int k = 0; k < 32; ++k) {
                float4 a0 = *(const float4*)(Slds + k * 128 + tb);
                float4 a1 = *(const float4*)(Slds + k * 128 + 64 + tb);
                float4 b0 = *(const float4*)(Wlds + k * 64 + ob);
                float4 b1 = *(const float4*)(Wlds + k * 64 + 32 + ob);
                float a[8]  = {a0.x, a0.y, a0.z, a0.w, a1.x, a1.y, a1.z, a1.w};
                float bv[8] = {b0.x, b0.y, b0.z, b0.w, b1.x, b1.y, b1.z, b1.w};
#pragma unroll
                for (int ii = 0; ii < 8; ++ii)
#pragma unroll
                    for (int jj = 0; jj < 8; ++jj)
                        acc[ii][jj] += a[ii] * bv[jj];
            }
            __syncthreads();
        }

#pragma unroll
        for (int ii = 0; ii < 8; ++ii) {
            int t = (ii >> 2) * 64 + tb + (ii & 3);
#pragma unroll
            for (int os = 0; os < 2; ++os) {
                float4 v = make_float4(acc[ii][os * 4 + 0], acc[ii][os * 4 + 1],
                                       acc[ii][os * 4 + 2], acc[ii][os * 4 + 3]);
                *(float4*)(Mlds + t * 68 + os * 32 + ob) = v;
            }
        }
        __syncthreads();

        if (tid < 64) {
#pragma unroll 4
            for (int t = 0; t < 128; ++t) {
                float x = Mlds[t * 68 + tid];
                mem = BETA_ * mem + x - spk * THRESH_;
                spk = (mem > THRESH_) ? 1.0f : 0.0f;
                cnt += spk;
            }
        }
        __syncthreads();
    }

    if (tid < 64) txCnt[(size_t)g * C_ + o0 + tid] = cnt;
}

// Full fused fallback (round 1) for tiny ws
__global__ __launch_bounds__(128) void lif_gemm_scan(
    const float* __restrict__ transmit, const float* __restrict__ receive,
    const float* __restrict__ Wtx, const float* __restrict__ btx,
    const float* __restrict__ Wrx, const float* __restrict__ brx,
    float* __restrict__ out, float* __restrict__ wsF)
{
    __shared__ float lds[128 * 68];
    float* Slds = lds;
    float* Wlds = lds + 4096;
    float* Mlds = lds;

    const int tid = threadIdx.x;
    const int bx  = blockIdx.x;
    const int ot  = bx / G_;
    const int g   = bx % G_;
    const int o0  = ot * 64;
    const bool isRx = (g >= 64);

    const float* Sg = isRx ? (receive + (size_t)(g - 64) * C_ * T_)
                           : (transmit + (size_t)g * C_ * T_);
    const float* Wp = isRx ? Wrx : Wtx;
    const float* bp = isRx ? brx : btx;

    const int ti = tid & 15;
    const int oi = tid >> 4;
    const int tb = ti * 4;
    const int ob = oi * 4;

    float bias[2][4];
#pragma unroll
    for (int os = 0; os < 2; ++os)
#pragma unroll
        for (int j = 0; j < 4; ++j)
            bias[os][j] = bp[o0 + os * 32 + ob + j];

    float mem = 0.f, spk = 0.f, cnt = 0.f;

    for (int tt = 0; tt < 8; ++tt) {
        const int t0 = tt * 128;
        float acc[8][8];
#pragma unroll
        for (int ii = 0; ii < 8; ++ii)
#pragma unroll
            for (int jj = 0; jj < 8; ++jj)
                acc[ii][jj] = bias[jj >> 2][jj & 3];

        for (int kk = 0; kk < 8; ++kk) {
            const int c0 = kk * 32;
#pragma unroll
            for (int p = 0; p < 8; ++p) {
                int idx = tid + p * 128;
                int c = idx >> 5, t4 = idx & 31;
                *(float4*)(Slds + c * 128 + t4 * 4) =
                    *(const float4*)(Sg + (size_t)(c0 + c) * T_ + t0 + t4 * 4);
            }
#pragma unroll
            for (int p = 0; p < 4; ++p) {
                int idx = tid + p * 128;
                int o = idx >> 3, c4 = idx & 7;
                float4 w = *(const float4*)(Wp + (size_t)(o0 + o) * C_ + c0 + c4 * 4);
                Wlds[(c4 * 4 + 0) * 64 + o] = w.x;
                Wlds[(c4 * 4 + 1) * 64 + o] = w.y;
                Wlds[(c4 * 4 + 2) * 64 + o] = w.z;
                Wlds[(c4 * 4 + 3) * 64 + o] = w.w;
            }
            __syncthreads();
#pragma unroll 8
            for (int k = 0; k < 32; ++k) {
                float4 a0 = *(const float4*)(Slds + k * 128 + tb);
                float4 a1 = *(const float4*)(Slds + k * 128 + 64 + tb);
                float4 b0 = *(const float4*)(Wlds + k * 64 + ob);
                float4 b1 = *(const float4*)(Wlds + k * 64 + 32 + ob);
                float a[8]  = {a0.x, a0.y, a0.z, a0.w, a1.x, a1.y, a1.z, a1.w};
                float bv[8] = {b0.x, b0.y, b0.z, b0.w, b1.x, b1.y, b1.z, b1.w};
#pragma unroll
                for (int ii = 0; ii < 8; ++ii)
#pragma unroll
                    for (int jj = 0; jj < 8; ++jj)
                        acc[ii][jj] += a[ii] * bv[jj];
            }
            __syncthreads();
        }

#pragma unroll
        for (int ii = 0; ii < 8; ++ii) {
            int t = (ii >> 2) * 64 + tb + (ii & 3);
#pragma unroll
            for (int os = 0; os < 2; ++os) {
                float4 v = make_float4(acc[ii][os * 4 + 0], acc[ii][os * 4 + 1],
                                       acc[ii][os * 4 + 2], acc[ii][os * 4 + 3]);
                *(float4*)(Mlds + t * 68 + os * 32 + ob) = v;
            }
        }
        __syncthreads();

        if (tid < 64) {
#pragma unroll 4
            for (int t = 0; t < 128; ++t) {
                float x = Mlds[t * 68 + tid];
                mem = BETA_ * mem + x - spk * THRESH_;
                spk = (mem > THRESH_) ? 1.0f : 0.0f;
                cnt += spk;
                Mlds[t * 68 + tid] = spk;
            }
        }
        __syncthreads();

        if (isRx) {
            float* dst = out + (size_t)OUT_RX + (size_t)(g - 64) * C_ * T_
                         + (size_t)o0 * T_ + t0;
            int m = tid & 7;
            int orow0 = tid >> 3;
#pragma unroll
            for (int p = 0; p < 4; ++p) {
                int orow = orow0 + p * 16;
#pragma unroll
                for (int q = 0; q < 4; ++q) {
                    int tq = m * 4 + q * 32;
                    float4 v = make_float4(Mlds[(tq + 0) * 68 + orow],
                                           Mlds[(tq + 1) * 68 + orow],
                                           Mlds[(tq + 2) * 68 + orow],
                                           Mlds[(tq + 3) * 68 + orow]);
                    *(float4*)(dst + (size_t)orow * T_ + tq) = v;
                }
            }
        }
        __syncthreads();
    }

    if (tid < 64) {
        if (isRx) out[(size_t)OUT_SP + (size_t)(g - 64) * C_ + o0 + tid] = cnt;
        else      wsF[(size_t)g * C_ + o0 + tid] = cnt;
    }
}

// Heads: layernorm over C=256 + GEMV to H=512, 3 heads x 64 batches
__global__ __launch_bounds__(256) void heads_kernel(
    const float* __restrict__ wsF, const float* __restrict__ sp,
    const float* __restrict__ Wd, const float* __restrict__ bd,
    const float* __restrict__ Wa, const float* __restrict__ ba,
    const float* __restrict__ We, const float* __restrict__ be,
    const float* __restrict__ gd, const float* __restrict__ ga, const float* __restrict__ ge,
    const float* __restrict__ based, const float* __restrict__ basea, const float* __restrict__ basee,
    float* __restrict__ out)
{
    __shared__ float fv[256];
    __shared__ float red[8];
    const int tid = threadIdx.x;
    const int hd  = blockIdx.x >> 6;
    const int b   = blockIdx.x & 63;

    float f;
    if (hd == 0) {
        f = wsF[b * 256 + tid] * (1.f / 1024.f);
    } else {
        float l = sp[(2 * b) * 256 + tid];
        float r = sp[(2 * b + 1) * 256 + tid];
        f = ((hd == 1) ? (l - r) : (l + r)) * (1.f / 1024.f);
    }

    float v = f;
#pragma unroll
    for (int off = 32; off > 0; off >>= 1) v += __shfl_down(v, off, 64);
    if ((tid & 63) == 0) red[tid >> 6] = v;
    __syncthreads();
    float mu = (red[0] + red[1] + red[2] + red[3]) * (1.f / 256.f);

    float d = f - mu;
    v = d * d;
#pragma unroll
    for (int off = 32; off > 0; off >>= 1) v += __shfl_down(v, off, 64);
    if ((tid & 63) == 0) red[4 + (tid >> 6)] = v;
    __syncthreads();
    float var  = (red[4] + red[5] + red[6] + red[7]) * (1.f / 256.f);
    float rstd = rsqrtf(var + 1e-5f);
    fv[tid] = d * rstd;
    __syncthreads();

    const float* W    = (hd == 0) ? Wd : (hd == 1) ? Wa : We;
    const float* bb   = (hd == 0) ? bd : (hd == 1) ? ba : be;
    const float* base = (hd == 0) ? based : (hd == 1) ? basea : basee;
    float gain = (hd == 0) ? gd[0] : (hd == 1) ? ga[0] : ge[0];
    float s = 0.3f / (1.f + expf(-gain));

    const float4* fv4 = (const float4*)fv;
#pragma unroll
    for (int hh = 0; hh < 2; ++hh) {
        int h = tid + hh * 256;
        const float4* W4 = (const float4*)(W + (size_t)h * 256);
        float acc = 0.f;
#pragma unroll 8
        for (int c = 0; c < 64; ++c) {
            float4 w = W4[c];
            float4 x = fv4[c];
            acc += w.x * x.x + w.y * x.y + w.z * x.z + w.w * x.w;
        }
        float r = acc + bb[h];
        float o = base[b * 512 + h] + s * r;
        out[(size_t)hd * (64 * 512) + b * 512 + h] = fmaxf(o, 0.f);
    }
}

extern "C" void kernel_launch(void* const* d_in, const int* in_sizes, int n_in,
                              void* d_out, int out_size, void* d_ws, size_t ws_size,
                              hipStream_t stream)
{
    const float* transmit = (const float*)d_in[0];
    const float* receive  = (const float*)d_in[1];
    const float* based    = (const float*)d_in[2];
    const float* basea    = (const float*)d_in[3];
    const float* basee    = (const float*)d_in[4];
    const float* Wtx      = (const float*)d_in[5];
    const float* btx      = (const float*)d_in[6];
    const float* Wrx      = (const float*)d_in[7];
    const float* brx      = (const float*)d_in[8];
    const float* Wd       = (const float*)d_in[9];
    const float* bd       = (const float*)d_in[10];
    const float* Wa       = (const float*)d_in[11];
    const float* ba       = (const float*)d_in[12];
    const float* We       = (const float*)d_in[13];
    const float* be       = (const float*)d_in[14];
    const float* gd       = (const float*)d_in[15];
    const float* ga       = (const float*)d_in[16];
    const float* ge       = (const float*)d_in[17];
    float* out = (float*)d_out;
    float* ws  = (float*)d_ws;

    const size_t tier2Need = (size_t)WS_MIXED * 4;                       // 576 KB
    const size_t tier1Need = tier2Need + (size_t)64 * T_ * C_ * 4;       // + 64 MB

    float* outRx = out + OUT_RX;
    float* spOut = out + OUT_SP;

    if (ws_size >= tier1Need) {
        // tier 1: split gemm for rx+tx, one scan kernel
        float* wtTx   = ws + WS_WT_TX;
        float* wtRx   = ws + WS_WT_RX;
        float* txCnt  = ws + WS_CNT;
        float* mixedT = ws + WS_MIXED;

        hipLaunchKernelGGL(transpose_w, dim3(128), dim3(256), 0, stream,
                           Wtx, Wrx, ws);
        hipLaunchKernelGGL(gemm_mix, dim3(8, 2, 128), dim3(256), 0, stream,
                           receive, wtRx, brx, outRx);
        hipLaunchKernelGGL(gemm_mix, dim3(8, 2, 64), dim3(256), 0, stream,
                           transmit, wtTx, btx, mixedT);
        hipLaunchKernelGGL(scan_quarter, dim3(768), dim3(64), 0, stream,
                           outRx, spOut, mixedT, txCnt);
        hipLaunchKernelGGL(heads_kernel, dim3(192), dim3(256), 0, stream,
                           txCnt, spOut, Wd, bd, Wa, ba, We, be,
                           gd, ga, ge, based, basea, basee, out);
    } else if (ws_size >= tier2Need) {
        // tier 2: split rx (in-place in out), fused tx
        float* wtRx   = ws + WS_WT_RX;
        float* txCnt  = ws + WS_CNT;

        hipLaunchKernelGGL(transpose_w, dim3(128), dim3(256), 0, stream,
                           Wtx, Wrx, ws);
        hipLaunchKernelGGL(gemm_mix, dim3(8, 2, 128), dim3(256), 0, stream,
                           receive, wtRx, brx, outRx);
        hipLaunchKernelGGL(lif_gemm_scan_tx, dim3(256), dim3(128), 0, stream,
                           transmit, Wtx, btx, txCnt);
        hipLaunchKernelGGL(scan_rx_only, dim3(512), dim3(64), 0, stream,
                           outRx, spOut);
        hipLaunchKernelGGL(heads_kernel, dim3(192), dim3(256), 0, stream,
                           txCnt, spOut, Wd, bd, Wa, ba, We, be,
                           gd, ga, ge, based, basea, basee, out);
    } else {
        // tier 3: round-1 fused fallback (64 KB ws)
        hipLaunchKernelGGL(lif_gemm_scan, dim3(768), dim3(128), 0, stream,
                           transmit, receive, Wtx, btx, Wrx, brx, out, ws);
        hipLaunchKernelGGL(heads_kernel, dim3(192), dim3(256), 0, stream,
                           ws, spOut, Wd, bd, Wa, ba, We, be,
                           gd, ga, ge, based, basea, basee, out);
    }
}